// Round 1
// baseline (2023.126 us; speedup 1.0000x reference)
//
#include <hip/hip_runtime.h>
#include <hip/hip_bf16.h>

#define BLOCK 256

// Online logsumexp merge: (m, s) <- merge((m, s), (mo, so))
__device__ __forceinline__ void lse_merge(float& m, float& s, float mo, float so) {
    float mn = fmaxf(m, mo);
    s = s * __expf(m - mn) + so * __expf(mo - mn);
    m = mn;
}

__device__ __forceinline__ void lse_push(float& m, float& s, float x) {
    float mn = fmaxf(m, x);
    s = s * __expf(m - mn) + __expf(x - mn);
    m = mn;
}

__global__ __launch_bounds__(BLOCK) void ce_loss_kernel(
    const float* __restrict__ input,
    const int* __restrict__ target,
    float* __restrict__ out,
    int B, int V)
{
    const int row = blockIdx.x;
    const int tid = threadIdx.x;
    const float* __restrict__ rp = input + (size_t)row * (size_t)V;

    float m = -1e30f;
    float s = 0.0f;

    // ---- alignment prologue: advance to 16B boundary (V odd -> rows not 16B aligned)
    int pro = (int)(((16u - ((unsigned)(uintptr_t)rp & 15u)) & 15u) >> 2);
    if (pro > V) pro = V;
    if (tid < pro) {
        lse_push(m, s, rp[tid]);
    }

    // ---- vectorized body: float4, coalesced, 16B/lane
    const int n4 = (V - pro) >> 2;
    const float4* __restrict__ rp4 = (const float4*)(rp + pro);
    for (int i = tid; i < n4; i += BLOCK) {
        float4 v = rp4[i];
        float xm = fmaxf(fmaxf(v.x, v.y), fmaxf(v.z, v.w));
        float mn = fmaxf(m, xm);
        s = s * __expf(m - mn)
          + __expf(v.x - mn) + __expf(v.y - mn)
          + __expf(v.z - mn) + __expf(v.w - mn);
        m = mn;
    }

    // ---- scalar tail
    const int tail_start = pro + (n4 << 2);
    const int ntail = V - tail_start;
    if (tid < ntail) {
        lse_push(m, s, rp[tail_start + tid]);
    }

    // ---- wave64 reduction
    #pragma unroll
    for (int off = 32; off > 0; off >>= 1) {
        float mo = __shfl_down(m, off, 64);
        float so = __shfl_down(s, off, 64);
        lse_merge(m, s, mo, so);
    }

    // ---- cross-wave reduction (4 waves)
    __shared__ float sh_m[BLOCK / 64];
    __shared__ float sh_s[BLOCK / 64];
    const int wave = tid >> 6;
    const int lane = tid & 63;
    if (lane == 0) { sh_m[wave] = m; sh_s[wave] = s; }
    __syncthreads();

    if (tid == 0) {
        float M = sh_m[0], S = sh_s[0];
        #pragma unroll
        for (int w = 1; w < BLOCK / 64; ++w) {
            lse_merge(M, S, sh_m[w], sh_s[w]);
        }
        const float picked = rp[target[row]];
        const float item_loss = (M + logf(S)) - picked;
        atomicAdd(out, item_loss * (1.0f / (float)B));
    }
}

extern "C" void kernel_launch(void* const* d_in, const int* in_sizes, int n_in,
                              void* d_out, int out_size, void* d_ws, size_t ws_size,
                              hipStream_t stream) {
    const float* input  = (const float*)d_in[0];
    const int*   target = (const int*)d_in[1];
    float*       out    = (float*)d_out;

    const int B = in_sizes[1];              // 8192
    const int V = in_sizes[0] / B;          // 50257

    // d_out is poisoned to 0xAA before every timed launch; we accumulate into it.
    hipMemsetAsync(d_out, 0, sizeof(float), stream);

    ce_loss_kernel<<<B, BLOCK, 0, stream>>>(input, target, out, B, V);
}